// Round 5
// baseline (295.623 us; speedup 1.0000x reference)
//
#include <hip/hip_runtime.h>
#include <stdint.h>

// B=4, N=1024, C=128, P=16 positions, HEADS=16, DH=128, D=2048, MASK_NUM=25, SCALE=0.125
typedef __attribute__((ext_vector_type(8))) short s8v;   // 8 bf16 (A/B frag)
typedef __attribute__((ext_vector_type(4))) short s4v;
typedef __attribute__((ext_vector_type(4))) float f4v;   // C/D frag

#define MFMA(a,b,c) __builtin_amdgcn_mfma_f32_16x16x32_bf16((a),(b),(c),0,0,0)

__device__ __forceinline__ short f2bf(float f){   // RNE float->bf16 bits
  union { float f; unsigned u; } a; a.f = f;
  unsigned r = (a.u + 0x7fffu + ((a.u >> 16) & 1u)) >> 16;
  return (short)r;
}
// truncating pack: (bf16(lo), bf16(hi)) in one v_perm_b32. Used ONLY for P
// (attention probs): numerator (P·V) and denominator (P·1) share the same
// truncated P, so the truncation bias cancels in the final ratio.
__device__ __forceinline__ unsigned pkt(float lo, float hi){
  return __builtin_amdgcn_perm(__float_as_uint(hi), __float_as_uint(lo), 0x07060302);
}

// async global->LDS DMA, 16B per lane; LDS dest = wave-uniform base + lane*16
__device__ __forceinline__ void gld16(const void* g, void* l){
  __builtin_amdgcn_global_load_lds((const __attribute__((address_space(1))) void*)g,
                                   (__attribute__((address_space(3))) void*)l, 16, 0, 0);
}

// ---------- weights fp32 -> bf16, + wcomb (block 0): wcomb[c]=sum Wl[o]Wq[o,c]; [128]=Wl.bq+bl ----------
__global__ void k_prep(const float* __restrict__ Wq, const float* __restrict__ Wk,
                       const float* __restrict__ Wv, const float* __restrict__ Wo,
                       const float* __restrict__ bq, const float* __restrict__ Wl,
                       const float* __restrict__ bl,
                       short* __restrict__ wq16, short* __restrict__ wk16,
                       short* __restrict__ wv16, short* __restrict__ wo16,
                       float* __restrict__ wcomb){
  int i = blockIdx.x*256 + threadIdx.x;      // grid 16384 -> exactly 4194304
  wo16[i] = f2bf(Wo[i]);
  if (i < 16384){ wq16[i] = f2bf(Wq[i]); wk16[i] = f2bf(Wk[i]); wv16[i] = f2bf(Wv[i]); }
  if (blockIdx.x == 0 && threadIdx.x < 128){
    int c = threadIdx.x;
    float s = 0.f;
    for (int o = 0; o < 128; ++o) s += Wl[o] * Wq[o*128 + c];
    wcomb[c] = s;
    if (c == 0){
      float t = 0.f; for (int o = 0; o < 128; ++o) t += Wl[o] * bq[o];
      wcomb[128] = t + bl[0];
    }
  }
}

// ---------- x fp32 -> bf16, plus fused logits (fp32) ----------
__global__ __launch_bounds__(256) void k_conv_x(const float* __restrict__ x, const float* __restrict__ wcomb,
                                                short* __restrict__ x16, float* __restrict__ logits){
  __shared__ float wc[128];
  __shared__ float part[4];
  int t = blockIdx.x, tid = threadIdx.x;     // one block per token
  if (tid < 128) wc[tid] = wcomb[tid];
  __syncthreads();
  const float* xp = x + (size_t)t*2048;
  short* op = x16 + (size_t)t*2048;
  float s = 0.f;
  #pragma unroll
  for (int j = 0; j < 2; ++j){
    int idx = j*1024 + tid*4;
    float4 v = *(const float4*)(xp + idx);
    s4v o; o.x = f2bf(v.x); o.y = f2bf(v.y); o.z = f2bf(v.z); o.w = f2bf(v.w);
    *(s4v*)(op + idx) = o;
    s += v.x*wc[idx&127] + v.y*wc[(idx+1)&127] + v.z*wc[(idx+2)&127] + v.w*wc[(idx+3)&127];
  }
  for (int off = 32; off; off >>= 1) s += __shfl_down(s, off);
  if ((tid&63) == 0) part[tid>>6] = s;
  __syncthreads();
  if (tid == 0) logits[t] = (part[0]+part[1]+part[2]+part[3])*(1.f/16.f) + wcomb[128];
}

// ---------- softmax + 25th-smallest threshold mask: one wave per batch ----------
__global__ __launch_bounds__(64) void k_mask(const float* __restrict__ logits, float* __restrict__ maskout){
  int b = blockIdx.x, lane = threadIdx.x;
  float v[16];
  #pragma unroll
  for (int i = 0; i < 16; ++i) v[i] = logits[b*1024 + i*64 + lane];
  float mx = v[0];
  #pragma unroll
  for (int i = 1; i < 16; ++i) mx = fmaxf(mx, v[i]);
  #pragma unroll
  for (int off = 32; off; off >>= 1) mx = fmaxf(mx, __shfl_xor(mx, off));
  float s = 0.f;
  #pragma unroll
  for (int i = 0; i < 16; ++i){ v[i] = __expf(v[i] - mx); s += v[i]; }
  #pragma unroll
  for (int off = 32; off; off >>= 1) s += __shfl_xor(s, off);
  float p[16];
  #pragma unroll
  for (int i = 0; i < 16; ++i){ p[i] = v[i] / s; v[i] = p[i]; }
  float thr = 0.f;
  for (int k = 0; k < 25; ++k){
    float lm = v[0]; int li = 0;
    #pragma unroll
    for (int i = 1; i < 16; ++i){ if (v[i] < lm){ lm = v[i]; li = i; } }
    float gm = lm;
    #pragma unroll
    for (int off = 32; off; off >>= 1) gm = fminf(gm, __shfl_xor(gm, off));
    if (k == 24) thr = gm;
    unsigned long long ball = __ballot(lm == gm);
    int owner = __ffsll((unsigned long long)ball) - 1;
    bool rm = (lane == owner);
    #pragma unroll
    for (int i = 0; i < 16; ++i){ if (rm && i == li) v[i] = 2.0f; }
  }
  #pragma unroll
  for (int i = 0; i < 16; ++i)
    maskout[b*1024 + i*64 + lane] = p[i] > thr ? 1.0f : p[i];
}

// ---------- merged QKV projection per (b, p, 64-token tile); Q pre-scaled 0.125*log2e;
//            mask folded into K and V; V written transposed to vt16 ----------
__global__ __launch_bounds__(256, 3) void k_qkv3(const short* __restrict__ x16,
                                              const short* __restrict__ wq16, const short* __restrict__ wk16,
                                              const short* __restrict__ wv16,
                                              const float* __restrict__ bq, const float* __restrict__ bk,
                                              const float* __restrict__ bv, const float* __restrict__ maskp,
                                              short* __restrict__ q16, short* __restrict__ k16,
                                              short* __restrict__ vt16){
  __shared__ short At[64*136];    // also reused as the V-transpose buffer T
  __shared__ short Wt[128*136];
  int tid = threadIdx.x, lane = tid&63, w = tid>>6;
  int n0 = blockIdx.x*64, p = blockIdx.y, b = blockIdx.z;
  #pragma unroll
  for (int i = 0; i < 4; ++i){
    int ch = tid + 256*i; int r = ch>>4, c8 = (ch&15)*8;
    *(s8v*)&At[r*136 + c8] = *(const s8v*)(x16 + (size_t)(b*1024 + n0 + r)*2048 + p*128 + c8);
  }
  int ln = lane&15, q = lane>>4;
  float mvr[4];
  #pragma unroll
  for (int r = 0; r < 4; ++r) mvr[r] = maskp[b*1024 + n0 + w*16 + q*4 + r];
  const short* ws[3] = {wq16, wk16, wv16};
  const float* bs[3] = {bq, bk, bv};
  for (int ps = 0; ps < 3; ++ps){
    if (ps) __syncthreads();   // prior pass's reads of Wt done
    #pragma unroll
    for (int i = 0; i < 8; ++i){
      int ch = tid + 256*i; int r = ch>>4, c8 = (ch&15)*8;
      *(s8v*)&Wt[r*136 + c8] = *(const s8v*)(ws[ps] + r*128 + c8);
    }
    __syncthreads();
    f4v acc[8];
    #pragma unroll
    for (int cb = 0; cb < 8; ++cb) acc[cb] = f4v{0.f,0.f,0.f,0.f};
    #pragma unroll
    for (int ks = 0; ks < 4; ++ks){
      s8v a = *(const s8v*)&At[(w*16+ln)*136 + ks*32 + q*8];
      #pragma unroll
      for (int cb = 0; cb < 8; ++cb){
        s8v bb = *(const s8v*)&Wt[(cb*16+ln)*136 + ks*32 + q*8];
        acc[cb] = MFMA(a, bb, acc[cb]);
      }
    }
    const float* bp = bs[ps];
    if (ps < 2){
      float sc = (ps == 0) ? 0.180336881f : 1.0f;   // Q: 0.125*log2(e); K: 1 (mask per-row)
      short* op = (ps == 0) ? q16 : k16;
      #pragma unroll
      for (int cb = 0; cb < 8; ++cb){
        int col = cb*16 + ln;
        float bv2 = bp[col];
        #pragma unroll
        for (int r = 0; r < 4; ++r){
          int n = n0 + w*16 + q*4 + r;
          float mm = (ps == 1) ? mvr[r] : 1.0f;
          op[(size_t)(b*1024 + n)*2048 + p*128 + col] = f2bf((acc[cb][r] + bv2)*sc*mm);
        }
      }
    } else {
      __syncthreads();  // all At (a-frag) reads done before overwrite as T
      #pragma unroll
      for (int cb = 0; cb < 8; ++cb){
        int col = cb*16 + ln;
        float bv2 = bp[col];
        #pragma unroll
        for (int r = 0; r < 4; ++r)
          At[(w*16 + q*4 + r)*136 + col] = f2bf((acc[cb][r] + bv2)*mvr[r]);  // vf = (v+b)*mask
      }
      __syncthreads();
      #pragma unroll
      for (int i = 0; i < 4; ++i){
        int ch = tid + 256*i; int c = ch>>3, n8 = (ch&7)*8;
        s8v o;
        #pragma unroll
        for (int j = 0; j < 8; ++j) o[j] = At[(n8+j)*136 + c];
        *(s8v*)(vt16 + (size_t)((b*16+p)*128 + c)*1024 + n0 + n8) = o;
      }
    }
  }
}

// ---------- flash attention per (b,h): S^T via K·Q^T (lane-local row stats), denominator via
//            ones-column MFMA; mask pre-folded into k16/vt16; exp2-domain softmax.
//            grid (h, it, b): linear id mod 8 = h mod 8 -> all it-blocks of one (b,h)
//            share an XCD, K/V slices cached once per XCD (4 MB = one L2). ----------
__global__ __launch_bounds__(256, 3) void k_attn(const short* __restrict__ q16, const short* __restrict__ k16,
                                                 const short* __restrict__ vt16, short* __restrict__ a16){
  __shared__ short Ks[64*128];   // row j(64) x 16 chunks of 8; LDS chunk c holds global chunk c^(r&7)
  __shared__ short Vs[128*64];   // row c(128) x 8 chunks; same XOR
  __shared__ short Ps[128*72];   // raw pp (truncated bf16), rows i-local x 64 j (stride 72)
  int h = blockIdx.x, it = blockIdx.y, b = blockIdx.z;
  int i0 = it*128;
  int tid = threadIdx.x, lane = tid&63, w = tid>>6;
  int ln = lane&15, q = lane>>4;
  // Q fragments (2 groups of 16 rows x K=128) as B-operands, in registers
  s8v aq[2][4];
  const short* qbase = q16 + (size_t)(b*1024 + i0 + w*32)*2048 + h*128;
  #pragma unroll
  for (int g = 0; g < 2; ++g)
    #pragma unroll
    for (int ks = 0; ks < 4; ++ks)
      aq[g][ks] = *(const s8v*)(qbase + (size_t)(g*16+ln)*2048 + ks*32 + q*8);
  s8v ones;
  #pragma unroll
  for (int j = 0; j < 8; ++j) ones[j] = (short)0x3F80;   // bf16 1.0
  f4v o[2][8], o9[2];
  #pragma unroll
  for (int g = 0; g < 2; ++g){
    #pragma unroll
    for (int cb = 0; cb < 8; ++cb) o[g][cb] = f4v{0.f,0.f,0.f,0.f};
    o9[g] = f4v{0.f,0.f,0.f,0.f};
  }
  float mo[2] = {-3.0e38f, -3.0e38f};
  const short* kbase = k16 + (size_t)(b*1024)*2048 + h*128;
  const short* vbase = vt16 + (size_t)((b*16+h)*128)*1024;
  for (int jt = 0; jt < 16; ++jt){
    int j0 = jt*64;
    __syncthreads();   // all waves done reading Ks/Vs of previous tile before DMA overwrite
    #pragma unroll
    for (int t = 0; t < 4; ++t){   // K: 4 rows x 16 chunks per wave-load
      int r = w*16 + t*4 + (lane>>4);
      int c = lane&15;
      gld16(kbase + (size_t)(j0 + r)*2048 + ((c ^ (r&7))*8), &Ks[(w*16 + t*4)*128]);
    }
    #pragma unroll
    for (int t = 0; t < 4; ++t){   // V: 8 rows x 8 chunks per wave-load
      int r = w*32 + t*8 + (lane>>3);
      int c = lane&7;
      gld16(vbase + (size_t)r*1024 + j0 + ((c ^ (r&7))*8), &Vs[(w*32 + t*8)*64]);
    }
    __syncthreads();   // DMA complete
    // S^T: rows j (mb*16 + q*4 + r), cols i (= ln, per group g)
    f4v st[2][4];
    #pragma unroll
    for (int g = 0; g < 2; ++g)
      #pragma unroll
      for (int mb = 0; mb < 4; ++mb) st[g][mb] = f4v{0.f,0.f,0.f,0.f};
    #pragma unroll
    for (int ks = 0; ks < 4; ++ks)
      #pragma unroll
      for (int mb = 0; mb < 4; ++mb){
        s8v ka = *(const s8v*)&Ks[(mb*16+ln)*128 + (((ks*4 + q) ^ (ln&7))*8)];
        st[0][mb] = MFMA(ka, aq[0][ks], st[0][mb]);
        st[1][mb] = MFMA(ka, aq[1][ks], st[1][mb]);
      }
    // softmax: each lane owns ONE Q-row per group (i = g*16+ln); j-coverage split over q-quads
    float alv[2];
    #pragma unroll
    for (int g = 0; g < 2; ++g){
      float mx = st[g][0][0];
      #pragma unroll
      for (int mb = 0; mb < 4; ++mb)
        #pragma unroll
        for (int r = 0; r < 4; ++r) mx = fmaxf(mx, st[g][mb][r]);
      mx = fmaxf(mx, __shfl_xor(mx, 16));
      mx = fmaxf(mx, __shfl_xor(mx, 32));
      float mnew = fmaxf(mo[g], mx);
      alv[g] = exp2f(mo[g] - mnew);
      mo[g] = mnew;
      int prow = (w*32 + g*16 + ln)*72;
      #pragma unroll
      for (int mb = 0; mb < 4; ++mb){
        uint2 u;
        u.x = pkt(exp2f(st[g][mb][0] - mnew), exp2f(st[g][mb][1] - mnew));
        u.y = pkt(exp2f(st[g][mb][2] - mnew), exp2f(st[g][mb][3] - mnew));
        *(uint2*)&Ps[prow + mb*16 + q*4] = u;
      }
    }
    // per-row alpha broadcast via in-wave shuffle (row q*4+r lives on lane q*4+r)
    float alr[2][4];
    #pragma unroll
    for (int g = 0; g < 2; ++g)
      #pragma unroll
      for (int r = 0; r < 4; ++r) alr[g][r] = __shfl(alv[g], q*4 + r);
    #pragma unroll
    for (int g = 0; g < 2; ++g){
      #pragma unroll
      for (int cb = 0; cb < 8; ++cb)
        #pragma unroll
        for (int r = 0; r < 4; ++r) o[g][cb][r] *= alr[g][r];
      #pragma unroll
      for (int r = 0; r < 4; ++r) o9[g][r] *= alr[g][r];
    }
    __syncthreads();   // Ps writes drained before b128 reads
    // PV: O[i][c] += P[i][j] V^T[c][j]; ones-column accumulates the denominator
    #pragma unroll
    for (int ks = 0; ks < 2; ++ks){
      s8v pa[2];
      #pragma unroll
      for (int g = 0; g < 2; ++g) pa[g] = *(const s8v*)&Ps[(w*32 + g*16 + ln)*72 + ks*32 + q*8];
      #pragma unroll
      for (int cb = 0; cb < 8; ++cb){
        s8v bb = *(const s8v*)&Vs[(cb*16+ln)*64 + (((ks*4 + q) ^ (ln&7))*8)];
        o[0][cb] = MFMA(pa[0], bb, o[0][cb]);
        o[1][cb] = MFMA(pa[1], bb, o[1][cb]);
      }
      o9[0] = MFMA(pa[0], ones, o9[0]);
      o9[1] = MFMA(pa[1], ones, o9[1]);
    }
  }
  #pragma unroll
  for (int g = 0; g < 2; ++g)
    #pragma unroll
    for (int cb = 0; cb < 8; ++cb){
      int col = cb*16 + ln;
      #pragma unroll
      for (int r = 0; r < 4; ++r){
        int row = i0 + w*32 + g*16 + q*4 + r;
        a16[(size_t)(b*1024 + row)*2048 + h*128 + col] = f2bf(o[g][cb][r] / o9[g][r]);
      }
    }
}

// ---------- output projection: out(4096,2048) = A16 . Wo^T + bo, global_load_lds + XOR-swizzled LDS ----------
__global__ __launch_bounds__(256) void k_out(const short* __restrict__ a16, const short* __restrict__ wo16,
                                             const float* __restrict__ bo, float* __restrict__ out){
  __shared__ short As[128*64];
  __shared__ short Bs[128*64];
  int tid = threadIdx.x, lane = tid&63, w = tid>>6;
  int m0 = blockIdx.x*128, n0 = blockIdx.y*128;
  int wrow = (w>>1)*64, wcol = (w&1)*64;
  int ln = lane&15, q = lane>>4;
  f4v acc[4][4];
  #pragma unroll
  for (int i = 0; i < 4; ++i)
    #pragma unroll
    for (int j = 0; j < 4; ++j) acc[i][j] = f4v{0.f,0.f,0.f,0.f};
  for (int it = 0; it < 32; ++it){
    int k0 = it*64;
    __syncthreads();
    #pragma unroll
    for (int t = 0; t < 4; ++t){   // 8 rows x 8 chunks per wave-load
      int r = w*32 + t*8 + (lane>>3);
      int c = lane&7;
      int gc8 = (c ^ (r&7))*8;
      gld16(a16  + (size_t)(m0+r)*2048 + k0 + gc8, &As[(w*32 + t*8)*64]);
      gld16(wo16 + (size_t)(n0+r)*2048 + k0 + gc8, &Bs[(w*32 + t*8)*64]);
    }
    __syncthreads();
    #pragma unroll
    for (int ks = 0; ks < 2; ++ks){
      s8v a[4], bb[4];
      int swz = ((ks*4 + q) ^ (ln&7))*8;
      #pragma unroll
      for (int i = 0; i < 4; ++i){
        a[i]  = *(const s8v*)&As[(wrow + i*16 + ln)*64 + swz];
        bb[i] = *(const s8v*)&Bs[(wcol + i*16 + ln)*64 + swz];
      }
      #pragma unroll
      for (int i = 0; i < 4; ++i)
        #pragma unroll
        for (int j = 0; j < 4; ++j) acc[i][j] = MFMA(a[i], bb[j], acc[i][j]);
    }
  }
  #pragma unroll
  for (int j = 0; j < 4; ++j){
    int col = n0 + wcol + j*16 + ln;
    float bv = bo[col];
    #pragma unroll
    for (int i = 0; i < 4; ++i)
      #pragma unroll
      for (int r = 0; r < 4; ++r){
        int row = m0 + wrow + i*16 + q*4 + r;
        out[(size_t)row*2048 + col] = acc[i][j][r] + bv;
      }
  }
}

extern "C" void kernel_launch(void* const* d_in, const int* in_sizes, int n_in,
                              void* d_out, int out_size, void* d_ws, size_t ws_size,
                              hipStream_t stream){
  const float* x  = (const float*)d_in[0];
  const float* Wq = (const float*)d_in[1];
  const float* bq = (const float*)d_in[2];
  const float* Wk = (const float*)d_in[3];
  const float* bk = (const float*)d_in[4];
  const float* Wv = (const float*)d_in[5];
  const float* bv = (const float*)d_in[6];
  const float* Wl = (const float*)d_in[7];
  const float* bl = (const float*)d_in[8];
  const float* Wo = (const float*)d_in[9];
  const float* bo = (const float*)d_in[10];
  float* out = (float*)d_out;

  char* p = (char*)d_ws;
  size_t off = 0;
  auto take = [&](size_t bytes)->char*{ char* r = p + off; off = (off + bytes + 255) & ~(size_t)255; return r; };
  short* x16   = (short*)take(16777216);  // (b,n,p,c) bf16; reused as attn-out after k_qkv3
  short* q16   = (short*)take(16777216);
  short* k16   = (short*)take(16777216);  // pre-masked kf
  short* vt16  = (short*)take(16777216);  // [b*16+h][c][n], pre-masked vf, transposed
  short* wo16  = (short*)take(8388608);
  short* wq16  = (short*)take(32768);
  short* wk16  = (short*)take(32768);
  short* wv16  = (short*)take(32768);
  float* wcomb = (float*)take(4*129);
  float* logits= (float*)take(4*4096);
  float* maskp = (float*)take(4*4096);
  short* a16 = x16;   // alias: x16 dead after k_qkv3

  k_prep  <<<16384, 256, 0, stream>>>(Wq, Wk, Wv, Wo, bq, Wl, bl, wq16, wk16, wv16, wo16, wcomb);
  k_conv_x<<<4096, 256, 0, stream>>>(x, wcomb, x16, logits);
  k_mask  <<<4, 64, 0, stream>>>(logits, maskp);
  k_qkv3  <<<dim3(16, 16, 4), 256, 0, stream>>>(x16, wq16, wk16, wv16, bq, bk, bv, maskp, q16, k16, vt16);
  k_attn  <<<dim3(16, 8, 4), 256, 0, stream>>>(q16, k16, vt16, a16);
  k_out   <<<dim3(32, 16), 256, 0, stream>>>(a16, wo16, bo, out);
}

// Round 6
// 257.294 us; speedup vs baseline: 1.1490x; 1.1490x over previous
//
#include <hip/hip_runtime.h>
#include <stdint.h>

// B=4, N=1024, C=128, P=16 positions, HEADS=16, DH=128, D=2048, MASK_NUM=25, SCALE=0.125
typedef __attribute__((ext_vector_type(8))) short s8v;   // 8 bf16 (A/B frag)
typedef __attribute__((ext_vector_type(4))) short s4v;
typedef __attribute__((ext_vector_type(4))) float f4v;   // C/D frag

#define MFMA(a,b,c) __builtin_amdgcn_mfma_f32_16x16x32_bf16((a),(b),(c),0,0,0)

__device__ __forceinline__ short f2bf(float f){   // RNE float->bf16 bits
  union { float f; unsigned u; } a; a.f = f;
  unsigned r = (a.u + 0x7fffu + ((a.u >> 16) & 1u)) >> 16;
  return (short)r;
}
// truncating pack: (bf16(lo), bf16(hi)) in one v_perm_b32. Used ONLY for P
// (attention probs): numerator (P·V) and denominator (P·1) share the same
// truncated P, so the truncation bias cancels in the final ratio.
__device__ __forceinline__ unsigned pkt(float lo, float hi){
  return __builtin_amdgcn_perm(__float_as_uint(hi), __float_as_uint(lo), 0x07060302);
}

// async global->LDS DMA, 16B per lane; LDS dest = wave-uniform base + lane*16
__device__ __forceinline__ void gld16(const void* g, void* l){
  __builtin_amdgcn_global_load_lds((const __attribute__((address_space(1))) void*)g,
                                   (__attribute__((address_space(3))) void*)l, 16, 0, 0);
}

// ---------- weights fp32 -> bf16, + wcomb (block 0): wcomb[c]=sum Wl[o]Wq[o,c]; [128]=Wl.bq+bl ----------
__global__ void k_prep(const float* __restrict__ Wq, const float* __restrict__ Wk,
                       const float* __restrict__ Wv, const float* __restrict__ Wo,
                       const float* __restrict__ bq, const float* __restrict__ Wl,
                       const float* __restrict__ bl,
                       short* __restrict__ wq16, short* __restrict__ wk16,
                       short* __restrict__ wv16, short* __restrict__ wo16,
                       float* __restrict__ wcomb){
  int i = blockIdx.x*256 + threadIdx.x;      // grid 16384 -> exactly 4194304
  wo16[i] = f2bf(Wo[i]);
  if (i < 16384){ wq16[i] = f2bf(Wq[i]); wk16[i] = f2bf(Wk[i]); wv16[i] = f2bf(Wv[i]); }
  if (blockIdx.x == 0 && threadIdx.x < 128){
    int c = threadIdx.x;
    float s = 0.f;
    for (int o = 0; o < 128; ++o) s += Wl[o] * Wq[o*128 + c];
    wcomb[c] = s;
    if (c == 0){
      float t = 0.f; for (int o = 0; o < 128; ++o) t += Wl[o] * bq[o];
      wcomb[128] = t + bl[0];
    }
  }
}

// ---------- x fp32 -> bf16, plus fused logits (fp32) ----------
__global__ __launch_bounds__(256) void k_conv_x(const float* __restrict__ x, const float* __restrict__ wcomb,
                                                short* __restrict__ x16, float* __restrict__ logits){
  __shared__ float wc[128];
  __shared__ float part[4];
  int t = blockIdx.x, tid = threadIdx.x;     // one block per token
  if (tid < 128) wc[tid] = wcomb[tid];
  __syncthreads();
  const float* xp = x + (size_t)t*2048;
  short* op = x16 + (size_t)t*2048;
  float s = 0.f;
  #pragma unroll
  for (int j = 0; j < 2; ++j){
    int idx = j*1024 + tid*4;
    float4 v = *(const float4*)(xp + idx);
    s4v o; o.x = f2bf(v.x); o.y = f2bf(v.y); o.z = f2bf(v.z); o.w = f2bf(v.w);
    *(s4v*)(op + idx) = o;
    s += v.x*wc[idx&127] + v.y*wc[(idx+1)&127] + v.z*wc[(idx+2)&127] + v.w*wc[(idx+3)&127];
  }
  for (int off = 32; off; off >>= 1) s += __shfl_down(s, off);
  if ((tid&63) == 0) part[tid>>6] = s;
  __syncthreads();
  if (tid == 0) logits[t] = (part[0]+part[1]+part[2]+part[3])*(1.f/16.f) + wcomb[128];
}

// ---------- softmax + 25th-smallest threshold mask: one wave per batch ----------
__global__ __launch_bounds__(64) void k_mask(const float* __restrict__ logits, float* __restrict__ maskout){
  int b = blockIdx.x, lane = threadIdx.x;
  float v[16];
  #pragma unroll
  for (int i = 0; i < 16; ++i) v[i] = logits[b*1024 + i*64 + lane];
  float mx = v[0];
  #pragma unroll
  for (int i = 1; i < 16; ++i) mx = fmaxf(mx, v[i]);
  #pragma unroll
  for (int off = 32; off; off >>= 1) mx = fmaxf(mx, __shfl_xor(mx, off));
  float s = 0.f;
  #pragma unroll
  for (int i = 0; i < 16; ++i){ v[i] = __expf(v[i] - mx); s += v[i]; }
  #pragma unroll
  for (int off = 32; off; off >>= 1) s += __shfl_xor(s, off);
  float p[16];
  #pragma unroll
  for (int i = 0; i < 16; ++i){ p[i] = v[i] / s; v[i] = p[i]; }
  float thr = 0.f;
  for (int k = 0; k < 25; ++k){
    float lm = v[0]; int li = 0;
    #pragma unroll
    for (int i = 1; i < 16; ++i){ if (v[i] < lm){ lm = v[i]; li = i; } }
    float gm = lm;
    #pragma unroll
    for (int off = 32; off; off >>= 1) gm = fminf(gm, __shfl_xor(gm, off));
    if (k == 24) thr = gm;
    unsigned long long ball = __ballot(lm == gm);
    int owner = __ffsll((unsigned long long)ball) - 1;
    bool rm = (lane == owner);
    #pragma unroll
    for (int i = 0; i < 16; ++i){ if (rm && i == li) v[i] = 2.0f; }
  }
  #pragma unroll
  for (int i = 0; i < 16; ++i)
    maskout[b*1024 + i*64 + lane] = p[i] > thr ? 1.0f : p[i];
}

// ---------- merged QKV projection per (b, p, 64-token tile); Q pre-scaled 0.125*log2e;
//            mask folded into K and V; V written transposed to vt16 ----------
__global__ __launch_bounds__(256) void k_qkv3(const short* __restrict__ x16,
                                              const short* __restrict__ wq16, const short* __restrict__ wk16,
                                              const short* __restrict__ wv16,
                                              const float* __restrict__ bq, const float* __restrict__ bk,
                                              const float* __restrict__ bv, const float* __restrict__ maskp,
                                              short* __restrict__ q16, short* __restrict__ k16,
                                              short* __restrict__ vt16){
  __shared__ short At[64*136];    // also reused as the V-transpose buffer T
  __shared__ short Wt[128*136];
  int tid = threadIdx.x, lane = tid&63, w = tid>>6;
  int n0 = blockIdx.x*64, p = blockIdx.y, b = blockIdx.z;
  #pragma unroll
  for (int i = 0; i < 4; ++i){
    int ch = tid + 256*i; int r = ch>>4, c8 = (ch&15)*8;
    *(s8v*)&At[r*136 + c8] = *(const s8v*)(x16 + (size_t)(b*1024 + n0 + r)*2048 + p*128 + c8);
  }
  int ln = lane&15, q = lane>>4;
  float mvr[4];
  #pragma unroll
  for (int r = 0; r < 4; ++r) mvr[r] = maskp[b*1024 + n0 + w*16 + q*4 + r];
  const short* ws[3] = {wq16, wk16, wv16};
  const float* bs[3] = {bq, bk, bv};
  for (int ps = 0; ps < 3; ++ps){
    if (ps) __syncthreads();   // prior pass's reads of Wt done
    #pragma unroll
    for (int i = 0; i < 8; ++i){
      int ch = tid + 256*i; int r = ch>>4, c8 = (ch&15)*8;
      *(s8v*)&Wt[r*136 + c8] = *(const s8v*)(ws[ps] + r*128 + c8);
    }
    __syncthreads();
    f4v acc[8];
    #pragma unroll
    for (int cb = 0; cb < 8; ++cb) acc[cb] = f4v{0.f,0.f,0.f,0.f};
    #pragma unroll
    for (int ks = 0; ks < 4; ++ks){
      s8v a = *(const s8v*)&At[(w*16+ln)*136 + ks*32 + q*8];
      #pragma unroll
      for (int cb = 0; cb < 8; ++cb){
        s8v bb = *(const s8v*)&Wt[(cb*16+ln)*136 + ks*32 + q*8];
        acc[cb] = MFMA(a, bb, acc[cb]);
      }
    }
    const float* bp = bs[ps];
    if (ps < 2){
      float sc = (ps == 0) ? 0.180336881f : 1.0f;   // Q: 0.125*log2(e); K: 1 (mask per-row)
      short* op = (ps == 0) ? q16 : k16;
      #pragma unroll
      for (int cb = 0; cb < 8; ++cb){
        int col = cb*16 + ln;
        float bv2 = bp[col];
        #pragma unroll
        for (int r = 0; r < 4; ++r){
          int n = n0 + w*16 + q*4 + r;
          float mm = (ps == 1) ? mvr[r] : 1.0f;
          op[(size_t)(b*1024 + n)*2048 + p*128 + col] = f2bf((acc[cb][r] + bv2)*sc*mm);
        }
      }
    } else {
      __syncthreads();  // all At (a-frag) reads done before overwrite as T
      #pragma unroll
      for (int cb = 0; cb < 8; ++cb){
        int col = cb*16 + ln;
        float bv2 = bp[col];
        #pragma unroll
        for (int r = 0; r < 4; ++r)
          At[(w*16 + q*4 + r)*136 + col] = f2bf((acc[cb][r] + bv2)*mvr[r]);  // vf = (v+b)*mask
      }
      __syncthreads();
      #pragma unroll
      for (int i = 0; i < 4; ++i){
        int ch = tid + 256*i; int c = ch>>3, n8 = (ch&7)*8;
        s8v o;
        #pragma unroll
        for (int j = 0; j < 8; ++j) o[j] = At[(n8+j)*136 + c];
        *(s8v*)(vt16 + (size_t)((b*16+p)*128 + c)*1024 + n0 + n8) = o;
      }
    }
  }
}

// ---------- flash attention per (b,h): S^T via K·Q^T (lane-local row stats), denominator via
//            ones-column MFMA; mask pre-folded into k16/vt16; exp2-domain softmax.
//            grid (h, it, b): linear id mod 8 = h mod 8 -> all it-blocks of one (b,h)
//            share an XCD, K/V slices cached once per XCD (4 MB = one L2).
//            launch_bounds (256,2): (256,3) forced VGPR 84 -> spills (R5: WRITE +18MB, dur +37us) ----------
__global__ __launch_bounds__(256, 2) void k_attn(const short* __restrict__ q16, const short* __restrict__ k16,
                                                 const short* __restrict__ vt16, short* __restrict__ a16){
  __shared__ short Ks[64*128];   // row j(64) x 16 chunks of 8; LDS chunk c holds global chunk c^(r&7)
  __shared__ short Vs[128*64];   // row c(128) x 8 chunks; same XOR
  __shared__ short Ps[128*72];   // raw pp (truncated bf16), rows i-local x 64 j (stride 72)
  int h = blockIdx.x, it = blockIdx.y, b = blockIdx.z;
  int i0 = it*128;
  int tid = threadIdx.x, lane = tid&63, w = tid>>6;
  int ln = lane&15, q = lane>>4;
  // Q fragments (2 groups of 16 rows x K=128) as B-operands, in registers
  s8v aq[2][4];
  const short* qbase = q16 + (size_t)(b*1024 + i0 + w*32)*2048 + h*128;
  #pragma unroll
  for (int g = 0; g < 2; ++g)
    #pragma unroll
    for (int ks = 0; ks < 4; ++ks)
      aq[g][ks] = *(const s8v*)(qbase + (size_t)(g*16+ln)*2048 + ks*32 + q*8);
  s8v ones;
  #pragma unroll
  for (int j = 0; j < 8; ++j) ones[j] = (short)0x3F80;   // bf16 1.0
  f4v o[2][8], o9[2];
  #pragma unroll
  for (int g = 0; g < 2; ++g){
    #pragma unroll
    for (int cb = 0; cb < 8; ++cb) o[g][cb] = f4v{0.f,0.f,0.f,0.f};
    o9[g] = f4v{0.f,0.f,0.f,0.f};
  }
  float mo[2] = {-3.0e38f, -3.0e38f};
  const short* kbase = k16 + (size_t)(b*1024)*2048 + h*128;
  const short* vbase = vt16 + (size_t)((b*16+h)*128)*1024;
  for (int jt = 0; jt < 16; ++jt){
    int j0 = jt*64;
    __syncthreads();   // all waves done reading Ks/Vs of previous tile before DMA overwrite
    #pragma unroll
    for (int t = 0; t < 4; ++t){   // K: 4 rows x 16 chunks per wave-load
      int r = w*16 + t*4 + (lane>>4);
      int c = lane&15;
      gld16(kbase + (size_t)(j0 + r)*2048 + ((c ^ (r&7))*8), &Ks[(w*16 + t*4)*128]);
    }
    #pragma unroll
    for (int t = 0; t < 4; ++t){   // V: 8 rows x 8 chunks per wave-load
      int r = w*32 + t*8 + (lane>>3);
      int c = lane&7;
      gld16(vbase + (size_t)r*1024 + j0 + ((c ^ (r&7))*8), &Vs[(w*32 + t*8)*64]);
    }
    __syncthreads();   // DMA complete
    // S^T: rows j (mb*16 + q*4 + r), cols i (= ln, per group g)
    f4v st[2][4];
    #pragma unroll
    for (int g = 0; g < 2; ++g)
      #pragma unroll
      for (int mb = 0; mb < 4; ++mb) st[g][mb] = f4v{0.f,0.f,0.f,0.f};
    #pragma unroll
    for (int ks = 0; ks < 4; ++ks)
      #pragma unroll
      for (int mb = 0; mb < 4; ++mb){
        s8v ka = *(const s8v*)&Ks[(mb*16+ln)*128 + (((ks*4 + q) ^ (ln&7))*8)];
        st[0][mb] = MFMA(ka, aq[0][ks], st[0][mb]);
        st[1][mb] = MFMA(ka, aq[1][ks], st[1][mb]);
      }
    // softmax: each lane owns ONE Q-row per group (i = g*16+ln); j-coverage split over q-quads
    float alv[2];
    #pragma unroll
    for (int g = 0; g < 2; ++g){
      float mx = st[g][0][0];
      #pragma unroll
      for (int mb = 0; mb < 4; ++mb)
        #pragma unroll
        for (int r = 0; r < 4; ++r) mx = fmaxf(mx, st[g][mb][r]);
      mx = fmaxf(mx, __shfl_xor(mx, 16));
      mx = fmaxf(mx, __shfl_xor(mx, 32));
      float mnew = fmaxf(mo[g], mx);
      alv[g] = exp2f(mo[g] - mnew);
      mo[g] = mnew;
      int prow = (w*32 + g*16 + ln)*72;
      #pragma unroll
      for (int mb = 0; mb < 4; ++mb){
        uint2 u;
        u.x = pkt(exp2f(st[g][mb][0] - mnew), exp2f(st[g][mb][1] - mnew));
        u.y = pkt(exp2f(st[g][mb][2] - mnew), exp2f(st[g][mb][3] - mnew));
        *(uint2*)&Ps[prow + mb*16 + q*4] = u;
      }
    }
    // per-row alpha broadcast via in-wave shuffle (row q*4+r lives on lane q*4+r)
    float alr[2][4];
    #pragma unroll
    for (int g = 0; g < 2; ++g)
      #pragma unroll
      for (int r = 0; r < 4; ++r) alr[g][r] = __shfl(alv[g], q*4 + r);
    #pragma unroll
    for (int g = 0; g < 2; ++g){
      #pragma unroll
      for (int cb = 0; cb < 8; ++cb)
        #pragma unroll
        for (int r = 0; r < 4; ++r) o[g][cb][r] *= alr[g][r];
      #pragma unroll
      for (int r = 0; r < 4; ++r) o9[g][r] *= alr[g][r];
    }
    __syncthreads();   // Ps writes drained before b128 reads
    // PV: O[i][c] += P[i][j] V^T[c][j]; ones-column accumulates the denominator
    #pragma unroll
    for (int ks = 0; ks < 2; ++ks){
      s8v pa[2];
      #pragma unroll
      for (int g = 0; g < 2; ++g) pa[g] = *(const s8v*)&Ps[(w*32 + g*16 + ln)*72 + ks*32 + q*8];
      #pragma unroll
      for (int cb = 0; cb < 8; ++cb){
        s8v bb = *(const s8v*)&Vs[(cb*16+ln)*64 + (((ks*4 + q) ^ (ln&7))*8)];
        o[0][cb] = MFMA(pa[0], bb, o[0][cb]);
        o[1][cb] = MFMA(pa[1], bb, o[1][cb]);
      }
      o9[0] = MFMA(pa[0], ones, o9[0]);
      o9[1] = MFMA(pa[1], ones, o9[1]);
    }
  }
  #pragma unroll
  for (int g = 0; g < 2; ++g)
    #pragma unroll
    for (int cb = 0; cb < 8; ++cb){
      int col = cb*16 + ln;
      #pragma unroll
      for (int r = 0; r < 4; ++r){
        int row = i0 + w*32 + g*16 + q*4 + r;
        a16[(size_t)(b*1024 + row)*2048 + h*128 + col] = f2bf(o[g][cb][r] / o9[g][r]);
      }
    }
}

// ---------- output projection: out(4096,2048) = A16 . Wo^T + bo, global_load_lds + XOR-swizzled LDS ----------
__global__ __launch_bounds__(256) void k_out(const short* __restrict__ a16, const short* __restrict__ wo16,
                                             const float* __restrict__ bo, float* __restrict__ out){
  __shared__ short As[128*64];
  __shared__ short Bs[128*64];
  int tid = threadIdx.x, lane = tid&63, w = tid>>6;
  int m0 = blockIdx.x*128, n0 = blockIdx.y*128;
  int wrow = (w>>1)*64, wcol = (w&1)*64;
  int ln = lane&15, q = lane>>4;
  f4v acc[4][4];
  #pragma unroll
  for (int i = 0; i < 4; ++i)
    #pragma unroll
    for (int j = 0; j < 4; ++j) acc[i][j] = f4v{0.f,0.f,0.f,0.f};
  for (int it = 0; it < 32; ++it){
    int k0 = it*64;
    __syncthreads();
    #pragma unroll
    for (int t = 0; t < 4; ++t){   // 8 rows x 8 chunks per wave-load
      int r = w*32 + t*8 + (lane>>3);
      int c = lane&7;
      int gc8 = (c ^ (r&7))*8;
      gld16(a16  + (size_t)(m0+r)*2048 + k0 + gc8, &As[(w*32 + t*8)*64]);
      gld16(wo16 + (size_t)(n0+r)*2048 + k0 + gc8, &Bs[(w*32 + t*8)*64]);
    }
    __syncthreads();
    #pragma unroll
    for (int ks = 0; ks < 2; ++ks){
      s8v a[4], bb[4];
      int swz = ((ks*4 + q) ^ (ln&7))*8;
      #pragma unroll
      for (int i = 0; i < 4; ++i){
        a[i]  = *(const s8v*)&As[(wrow + i*16 + ln)*64 + swz];
        bb[i] = *(const s8v*)&Bs[(wcol + i*16 + ln)*64 + swz];
      }
      #pragma unroll
      for (int i = 0; i < 4; ++i)
        #pragma unroll
        for (int j = 0; j < 4; ++j) acc[i][j] = MFMA(a[i], bb[j], acc[i][j]);
    }
  }
  #pragma unroll
  for (int j = 0; j < 4; ++j){
    int col = n0 + wcol + j*16 + ln;
    float bv = bo[col];
    #pragma unroll
    for (int i = 0; i < 4; ++i)
      #pragma unroll
      for (int r = 0; r < 4; ++r){
        int row = m0 + wrow + i*16 + q*4 + r;
        out[(size_t)row*2048 + col] = acc[i][j][r] + bv;
      }
  }
}

extern "C" void kernel_launch(void* const* d_in, const int* in_sizes, int n_in,
                              void* d_out, int out_size, void* d_ws, size_t ws_size,
                              hipStream_t stream){
  const float* x  = (const float*)d_in[0];
  const float* Wq = (const float*)d_in[1];
  const float* bq = (const float*)d_in[2];
  const float* Wk = (const float*)d_in[3];
  const float* bk = (const float*)d_in[4];
  const float* Wv = (const float*)d_in[5];
  const float* bv = (const float*)d_in[6];
  const float* Wl = (const float*)d_in[7];
  const float* bl = (const float*)d_in[8];
  const float* Wo = (const float*)d_in[9];
  const float* bo = (const float*)d_in[10];
  float* out = (float*)d_out;

  char* p = (char*)d_ws;
  size_t off = 0;
  auto take = [&](size_t bytes)->char*{ char* r = p + off; off = (off + bytes + 255) & ~(size_t)255; return r; };
  short* x16   = (short*)take(16777216);  // (b,n,p,c) bf16; reused as attn-out after k_qkv3
  short* q16   = (short*)take(16777216);
  short* k16   = (short*)take(16777216);  // pre-masked kf
  short* vt16  = (short*)take(16777216);  // [b*16+h][c][n], pre-masked vf, transposed
  short* wo16  = (short*)take(8388608);
  short* wq16  = (short*)take(32768);
  short* wk16  = (short*)take(32768);
  short* wv16  = (short*)take(32768);
  float* wcomb = (float*)take(4*129);
  float* logits= (float*)take(4*4096);
  float* maskp = (float*)take(4*4096);
  short* a16 = x16;   // alias: x16 dead after k_qkv3

  k_prep  <<<16384, 256, 0, stream>>>(Wq, Wk, Wv, Wo, bq, Wl, bl, wq16, wk16, wv16, wo16, wcomb);
  k_conv_x<<<4096, 256, 0, stream>>>(x, wcomb, x16, logits);
  k_mask  <<<4, 64, 0, stream>>>(logits, maskp);
  k_qkv3  <<<dim3(16, 16, 4), 256, 0, stream>>>(x16, wq16, wk16, wv16, bq, bk, bv, maskp, q16, k16, vt16);
  k_attn  <<<dim3(16, 8, 4), 256, 0, stream>>>(q16, k16, vt16, a16);
  k_out   <<<dim3(32, 16), 256, 0, stream>>>(a16, wo16, bo, out);
}